// Round 4
// baseline (615.410 us; speedup 1.0000x reference)
//
#include <hip/hip_runtime.h>
#include <hip/hip_bf16.h>

typedef __bf16 bf16;
typedef __bf16 bf16x4 __attribute__((ext_vector_type(4)));
typedef __bf16 bf16x8 __attribute__((ext_vector_type(8)));
typedef float f32x4 __attribute__((ext_vector_type(4)));

#define B_ 2
#define H_ 32
#define HKV_ 8
#define S_ 2048
#define D_ 128
#define QT 64
#define KT 64
#define KST 136   // K LDS row stride (elems): 272B/row, 16B-aligned chunks
#define VST 68    // V^T LDS row stride: 136B/row (R3 showed 72 doubles conflicts)
#define PST 72    // P LDS row stride: 144B/row, 16B-aligned
#define NEG_BIG (-1.0e30f)
#define SCL 0.12751745f  // (1/sqrt(128)) * log2(e): softmax in exp2 domain
#define DEFER_THR 8.0f   // T13: skip O-rescale while max grows < 2^8

__device__ __forceinline__ bf16x8 cvt8p(float4 a, float4 b) {
  bf16x8 r = {(bf16)a.x, (bf16)a.y, (bf16)a.z, (bf16)a.w,
              (bf16)b.x, (bf16)b.y, (bf16)b.z, (bf16)b.w};
  return r;
}
__device__ __forceinline__ bf16x8 cvt8(const float* f) {
  return cvt8p(*(const float4*)f, *(const float4*)(f + 4));
}

// R4: depth-2 register pipeline. issue(j+2) loads are USED by commit(j+2) in
// the NEXT loop iteration -- the use sits across the back-edge, so the
// compiler cannot sink the loads to their use (R1/R3 failure mode) and must
// keep them live in VGPRs across compute. The vmcnt wait in commit() lands a
// full iteration after issue -> load latency fully hidden. All loads are
// compiler-managed (no R2 undefined-register hazard).
__global__ __launch_bounds__(256, 3) void fa_mfma(
    const float* __restrict__ q, const float* __restrict__ k,
    const float* __restrict__ v, float* __restrict__ out) {
  __shared__ bf16 Ks[KT * KST];      // K tile [key][d]
  __shared__ bf16 Vt[D_ * VST];      // V tile transposed [d][key]
  __shared__ bf16 Ps[4 * 16 * PST];  // per-wave P [qrow][key]

  const int tid = threadIdx.x, wave = tid >> 6, lane = tid & 63;
  const int col = lane & 15, quad = lane >> 4;
  const int bid = blockIdx.x;
  const int tq = 31 - (bid & 31);  // diagonal-heavy tiles first
  const int bh = bid >> 5, b = bh >> 5, h = bh & 31, hkv = h >> 2;  // GQA h/4

  const float* qh = q + (size_t)(b * H_ + h) * S_ * D_;
  const float* kh = k + (size_t)(b * HKV_ + hkv) * S_ * D_;
  const float* vh = v + (size_t)(b * HKV_ + hkv) * S_ * D_;
  float* oh = out + (size_t)(b * H_ + h) * S_ * D_;
  const int q0 = tq * QT;

  // Q A-fragments: A[m=lane&15][k=quad*8+j], chunk ks covers d in [ks*32,ks*32+32)
  bf16x8 qf[4];
  {
    const float* qrow = qh + (size_t)(q0 + wave * 16 + col) * D_ + quad * 8;
#pragma unroll
    for (int ks = 0; ks < 4; ++ks) qf[ks] = cvt8(qrow + ks * 32);
  }

  f32x4 o[8];
#pragma unroll
  for (int i = 0; i < 8; ++i) o[i] = (f32x4){0.f, 0.f, 0.f, 0.f};
  float m_i[4], lp[4];  // lp: per-lane PARTIAL l (reduced across 16 lanes only
                        // in the epilogue; alpha is row-uniform so this is exact)
#pragma unroll
  for (int r = 0; r < 4; ++r) { m_i[r] = NEG_BIG; lp[r] = 0.f; }

  // staging geometry
  const int krow = tid >> 4, kcc = tid & 15;  // K: rows krow+16*i, 16B col kcc
  const int kb = (tid >> 4) * 4;              // V: 4 consecutive keys
  const int dofs = (tid & 15) * 8;            // V: 8 consecutive d

  float4 kpre[8], vpre[8];  // in-flight tile, live across the back-edge

  auto issue = [&](int j) {  // plain loads; used by NEXT iteration's commit
    const float* kbase = kh + (size_t)j * KT * D_;
    const float* vbase = vh + (size_t)j * KT * D_;
#pragma unroll
    for (int i = 0; i < 4; ++i) {
      const float* p = kbase + (size_t)(krow + 16 * i) * D_ + kcc * 8;
      kpre[2 * i] = *(const float4*)p;
      kpre[2 * i + 1] = *(const float4*)(p + 4);
    }
#pragma unroll
    for (int i = 0; i < 4; ++i) {
      const float* p = vbase + (size_t)(kb + i) * D_ + dofs;
      vpre[2 * i] = *(const float4*)p;
      vpre[2 * i + 1] = *(const float4*)(p + 4);
    }
  };

  auto commit = [&]() {  // f32->bf16 + LDS write (vmcnt wait auto-inserted,
                         // ~1 iteration after the loads were issued)
#pragma unroll
    for (int i = 0; i < 4; ++i)
      *(bf16x8*)&Ks[(krow + 16 * i) * KST + kcc * 8] =
          cvt8p(kpre[2 * i], kpre[2 * i + 1]);
    bf16x8 vv[4];
#pragma unroll
    for (int i = 0; i < 4; ++i) vv[i] = cvt8p(vpre[2 * i], vpre[2 * i + 1]);
#pragma unroll
    for (int jj = 0; jj < 8; ++jj) {
      bf16x4 pk = {vv[0][jj], vv[1][jj], vv[2][jj], vv[3][jj]};
      *(bf16x4*)&Vt[(dofs + jj) * VST + kb] = pk;
    }
  };

  issue(0);
  commit();        // cold start: immediate wait, once per block
  __syncthreads();
  issue(1);        // tile 1 in flight under compute(0). Harmless prefetch
                   // past the causal edge when tq==0 (still in-bounds).

  for (int j = 0; j <= tq; ++j) {
    // ---- S strip: 16 q-rows x 64 keys per wave ----
    float s[4][4];  // S[qrow=wave*16+quad*4+r][key=nt*16+col]
#pragma unroll
    for (int nt = 0; nt < 4; ++nt) {
      f32x4 acc = (f32x4){0.f, 0.f, 0.f, 0.f};
#pragma unroll
      for (int ks = 0; ks < 4; ++ks) {
        bf16x8 kf = *(const bf16x8*)&Ks[(nt * 16 + col) * KST + ks * 32 + quad * 8];
        acc = __builtin_amdgcn_mfma_f32_16x16x32_bf16(qf[ks], kf, acc, 0, 0, 0);
      }
#pragma unroll
      for (int r = 0; r < 4; ++r) s[nt][r] = acc[r] * SCL;
    }

    // causal mask on diagonal tile (key base == q base)
    if (j == tq) {
#pragma unroll
      for (int nt = 0; nt < 4; ++nt) {
        int kc = nt * 16 + col;
#pragma unroll
        for (int r = 0; r < 4; ++r)
          if (kc > wave * 16 + quad * 4 + r) s[nt][r] = NEG_BIG;
      }
    }

    // ---- online softmax: max-reduce only; l kept as per-lane partial ----
    float mx[4];
#pragma unroll
    for (int r = 0; r < 4; ++r) {
      float m0 = fmaxf(fmaxf(s[0][r], s[1][r]), fmaxf(s[2][r], s[3][r]));
#pragma unroll
      for (int off = 1; off < 16; off <<= 1)
        m0 = fmaxf(m0, __shfl_xor(m0, off, 64));
      mx[r] = m0;  // uniform across the row's 16 lanes
    }
    // T13 defer-max: wave-uniform skip of the O-rescale while growth < THR
    float need = fmaxf(fmaxf(mx[0] - m_i[0], mx[1] - m_i[1]),
                       fmaxf(mx[2] - m_i[2], mx[3] - m_i[3]));
    if (__any(need > DEFER_THR)) {
#pragma unroll
      for (int r = 0; r < 4; ++r) {
        float mnew = fmaxf(m_i[r], mx[r]);
        float alpha = exp2f(m_i[r] - mnew);
        lp[r] *= alpha;
        m_i[r] = mnew;
#pragma unroll
        for (int dt = 0; dt < 8; ++dt) o[dt][r] *= alpha;
      }
    }

    float p[4][4];
#pragma unroll
    for (int r = 0; r < 4; ++r) {
      float rs = 0.f;
#pragma unroll
      for (int nt = 0; nt < 4; ++nt) {
        float pv = exp2f(s[nt][r] - m_i[r]);  // bounded by 2^THR
        p[nt][r] = pv;
        rs += pv;
      }
      lp[r] += rs;
    }

    // ---- P: C-layout -> A-layout via per-wave LDS round trip ----
    bf16* pw = &Ps[wave * 16 * PST];
#pragma unroll
    for (int nt = 0; nt < 4; ++nt)
#pragma unroll
      for (int r = 0; r < 4; ++r)
        pw[(quad * 4 + r) * PST + nt * 16 + col] = (bf16)p[nt][r];
    asm volatile("s_waitcnt lgkmcnt(0)" ::: "memory");

    bf16x8 pf[2];
#pragma unroll
    for (int ks = 0; ks < 2; ++ks)
      pf[ks] = *(const bf16x8*)&pw[col * PST + ks * 32 + quad * 8];

    // ---- O += P·V (VST=68: rows 8B-aligned -> 2x b64 reads) ----
#pragma unroll
    for (int dt = 0; dt < 8; ++dt) {
#pragma unroll
      for (int ks = 0; ks < 2; ++ks) {
        const bf16* vb = &Vt[(dt * 16 + col) * VST + ks * 32 + quad * 8];
        bf16x4 lo = *(const bf16x4*)vb;
        bf16x4 hi = *(const bf16x4*)(vb + 4);
        bf16x8 vf = {lo[0], lo[1], lo[2], lo[3], hi[0], hi[1], hi[2], hi[3]};
        o[dt] = __builtin_amdgcn_mfma_f32_16x16x32_bf16(pf[ks], vf, o[dt], 0, 0, 0);
      }
    }

    // ---- rotate the pipeline ----
    if (j < tq) {
      __syncthreads();   // all waves done reading tile j
      commit();          // tile j+1: regs issued one iteration ago -> wait free
      __syncthreads();   // tile j+1 visible
      if (j + 1 < tq) issue(j + 2);  // in flight under compute(j+1)
    }
  }

  // ---- epilogue: reduce partial l across the row's 16 lanes, O / l ----
#pragma unroll
  for (int r = 0; r < 4; ++r) {
    float l = lp[r];
#pragma unroll
    for (int off = 1; off < 16; off <<= 1)
      l += __shfl_xor(l, off, 64);
    float inv = 1.f / l;
    float* orow = oh + (size_t)(q0 + wave * 16 + quad * 4 + r) * D_;
#pragma unroll
    for (int dt = 0; dt < 8; ++dt)
      orow[dt * 16 + col] = o[dt][r] * inv;
  }
}

extern "C" void kernel_launch(void* const* d_in, const int* in_sizes, int n_in,
                              void* d_out, int out_size, void* d_ws, size_t ws_size,
                              hipStream_t stream) {
  const int QN = B_ * H_ * S_ * D_;
  int qi, ki, vi;
  if (in_sizes[0] == QN)      { qi = 0; ki = 1; vi = 2; }
  else if (in_sizes[1] == QN) { qi = 1; ki = 0; vi = 2; }
  else                        { qi = 2; ki = 0; vi = 1; }
  const float* q = (const float*)d_in[qi];
  const float* k = (const float*)d_in[ki];
  const float* v = (const float*)d_in[vi];
  float* out = (float*)d_out;
  fa_mfma<<<dim3(2048), dim3(256), 0, stream>>>(q, k, v, out);
}

// Round 5
// 409.318 us; speedup vs baseline: 1.5035x; 1.5035x over previous
//
#include <hip/hip_runtime.h>
#include <hip/hip_bf16.h>
#include <cstdint>

typedef __bf16 bf16;
typedef __bf16 bf16x8 __attribute__((ext_vector_type(8)));
typedef float f32x4 __attribute__((ext_vector_type(4)));
typedef __attribute__((address_space(3))) uint32_t lds_u32;
typedef const __attribute__((address_space(1))) uint32_t glb_u32;

#define B_ 2
#define H_ 32
#define HKV_ 8
#define S_ 2048
#define D_ 128
#define QT 64
#define KT 64
#define NTILES (S_ / KT)       // 32
#define TILE_ELEMS (KT * D_)   // 8192 bf16 = 16 KiB per tile image
#define PST 72                 // P LDS row stride: 144B/row, 16B-aligned
#define NEG_BIG (-1.0e30f)
#define SCL 0.12751745f        // (1/sqrt(128)) * log2(e): softmax in exp2 domain
#define DEFER_THR 8.0f         // T13: skip O-rescale while max grows < 2^8

__device__ __forceinline__ bf16x8 cvt8p(float4 a, float4 b) {
  bf16x8 r = {(bf16)a.x, (bf16)a.y, (bf16)a.z, (bf16)a.w,
              (bf16)b.x, (bf16)b.y, (bf16)b.z, (bf16)b.w};
  return r;
}
__device__ __forceinline__ bf16x8 cvt8(const float* f) {
  return cvt8p(*(const float4*)f, *(const float4*)(f + 4));
}

// ---------------- pre-pass: build swizzled bf16 LDS tile images in ws -------
// K image, per (bhkv,tile): byte(row*256 + c16*16) holds K[row][(c16^(row&7))*8 ..+7]
// V image (transposed):     byte(d*128  + c8*16)  holds V[(c8^(d&7))*8 + t][d], t=0..7
// So a LINEAR global->LDS copy yields the XOR-swizzled layout (rule #21:
// linear dest + inverse-swizzled source + swizzled read).
__global__ __launch_bounds__(256) void prep(const float* __restrict__ k,
                                            const float* __restrict__ v,
                                            bf16* __restrict__ kws,
                                            bf16* __restrict__ vws) {
  const int blk = blockIdx.x;  // 512 = 16 (b*hkv) * 32 tiles
  const int bhkv = blk >> 5, tile = blk & 31;
  const float* ks = k + ((size_t)bhkv * S_ + (size_t)tile * KT) * D_;
  const float* vs = v + ((size_t)bhkv * S_ + (size_t)tile * KT) * D_;
  bf16* kd = kws + (size_t)blk * TILE_ELEMS;
  bf16* vd = vws + (size_t)blk * TILE_ELEMS;
  const int t = threadIdx.x;
#pragma unroll
  for (int i = 0; i < 4; ++i) {
    int chunk = t + 256 * i, row = chunk >> 4, c16 = chunk & 15;
    int e = (c16 ^ (row & 7)) << 3;  // 8 source elems
    *(bf16x8*)&kd[chunk * 8] = cvt8(ks + row * D_ + e);
  }
#pragma unroll
  for (int i = 0; i < 4; ++i) {
    int chunk = t + 256 * i, d = chunk >> 3, c8 = chunk & 7;
    int k0 = (c8 ^ (d & 7)) << 3;  // 8 source keys (transposed gather;
    bf16x8 val;                    // L2 absorbs the re-touch within the block)
#pragma unroll
    for (int kk = 0; kk < 8; ++kk) val[kk] = (bf16)vs[(size_t)(k0 + kk) * D_ + d];
    *(bf16x8*)&vd[chunk * 8] = val;
  }
}

// ---------------- main: flash attention with global_load_lds staging --------
// R5: staging = 8x global_load_lds dwordx4 per thread from the pre-built ws
// images (no VGPR round trip, no scratch, no in-loop cvt/transpose). Double-
// buffered LDS: issue(j+1 -> buf^1) at iteration top, compute(buf), drain at
// the end-of-iter barrier -> load latency hidden under the full compute.
__global__ __launch_bounds__(256, 2) void fa_mfma(
    const float* __restrict__ q, const bf16* __restrict__ kws,
    const bf16* __restrict__ vws, float* __restrict__ out) {
  __shared__ bf16 Kb2[2][TILE_ELEMS];  // 32 KiB
  __shared__ bf16 Vb2[2][TILE_ELEMS];  // 32 KiB
  __shared__ bf16 Ps[4 * 16 * PST];    // 9 KiB

  const int tid = threadIdx.x, wave = tid >> 6, lane = tid & 63;
  const int col = lane & 15, quad = lane >> 4;
  const int bid = blockIdx.x;
  const int tq = 31 - (bid & 31);  // diagonal-heavy tiles first
  const int bh = bid >> 5, b = bh >> 5, h = bh & 31, hkv = h >> 2;  // GQA h/4
  const int bhkv = b * HKV_ + hkv;

  const float* qh = q + (size_t)(b * H_ + h) * S_ * D_;
  float* oh = out + (size_t)(b * H_ + h) * S_ * D_;
  const bf16* kg = kws + (size_t)(bhkv * NTILES) * TILE_ELEMS;
  const bf16* vg = vws + (size_t)(bhkv * NTILES) * TILE_ELEMS;
  const int q0 = tq * QT;

  // Q A-fragments: A[m=col][k=quad*8+j], chunk ks covers d in [ks*32,ks*32+32)
  bf16x8 qf[4];
  {
    const float* qrow = qh + (size_t)(q0 + wave * 16 + col) * D_ + quad * 8;
#pragma unroll
    for (int ks = 0; ks < 4; ++ks) qf[ks] = cvt8(qrow + ks * 32);
  }

  f32x4 o[8];
#pragma unroll
  for (int i = 0; i < 8; ++i) o[i] = (f32x4){0.f, 0.f, 0.f, 0.f};
  float m_i[4], lp[4];  // lp: per-lane PARTIAL l; reduced in the epilogue
#pragma unroll
  for (int r = 0; r < 4; ++r) { m_i[r] = NEG_BIG; lp[r] = 0.f; }

  // swizzled-read offsets: row&7 == col&7 for both K (row=nt*16+col) and
  // V (d=dt*16+col); qx[ks] = (quad*16 ^ xk) ^ ks*64 (disjoint-bit sum = XOR)
  const int xk = (col & 7) << 4;
  const int qoff = (quad * 16) ^ xk;
  const int qx[4] = {qoff, qoff ^ 64, qoff ^ 128, qoff ^ 192};

  const int stoff = wave * 4096 + lane * 16;  // staging byte offset

  auto stage = [&](int j, int buf) {  // async; drained at end-of-iter barrier
    const char* kp = (const char*)(kg + (size_t)j * TILE_ELEMS) + stoff;
    const char* vp = (const char*)(vg + (size_t)j * TILE_ELEMS) + stoff;
    char* kl = (char*)Kb2[buf] + stoff;
    char* vl = (char*)Vb2[buf] + stoff;
#pragma unroll
    for (int i = 0; i < 4; ++i)
      __builtin_amdgcn_global_load_lds((glb_u32*)(kp + i * 1024),
                                       (lds_u32*)(kl + i * 1024), 16, 0, 0);
#pragma unroll
    for (int i = 0; i < 4; ++i)
      __builtin_amdgcn_global_load_lds((glb_u32*)(vp + i * 1024),
                                       (lds_u32*)(vl + i * 1024), 16, 0, 0);
  };

  stage(0, 0);
  asm volatile("s_waitcnt vmcnt(0)" ::: "memory");
  __syncthreads();

  for (int j = 0; j <= tq; ++j) {
    const int cur = j & 1;
    if (j < tq) stage(j + 1, cur ^ 1);  // in flight under this whole iteration

    const char* Kb = (const char*)Kb2[cur];
    const char* Vb = (const char*)Vb2[cur];

    // ---- S strip: 16 q-rows x 64 keys per wave (swizzled b128 reads) ----
    float s[4][4];  // S[qrow=wave*16+quad*4+r][key=nt*16+col]
#pragma unroll
    for (int nt = 0; nt < 4; ++nt) {
      const char* An = Kb + (nt * 16 + col) * 256;
      f32x4 acc = (f32x4){0.f, 0.f, 0.f, 0.f};
#pragma unroll
      for (int ks = 0; ks < 4; ++ks) {
        bf16x8 kf = *(const bf16x8*)(An + qx[ks]);
        acc = __builtin_amdgcn_mfma_f32_16x16x32_bf16(qf[ks], kf, acc, 0, 0, 0);
      }
#pragma unroll
      for (int r = 0; r < 4; ++r) s[nt][r] = acc[r] * SCL;
    }

    // causal mask on diagonal tile (key base == q base)
    if (j == tq) {
#pragma unroll
      for (int nt = 0; nt < 4; ++nt) {
        int kc = nt * 16 + col;
#pragma unroll
        for (int r = 0; r < 4; ++r)
          if (kc > wave * 16 + quad * 4 + r) s[nt][r] = NEG_BIG;
      }
    }

    // ---- online softmax: max-reduce only; l kept as per-lane partial ----
    float mx[4];
#pragma unroll
    for (int r = 0; r < 4; ++r) {
      float m0 = fmaxf(fmaxf(s[0][r], s[1][r]), fmaxf(s[2][r], s[3][r]));
#pragma unroll
      for (int off = 1; off < 16; off <<= 1)
        m0 = fmaxf(m0, __shfl_xor(m0, off, 64));
      mx[r] = m0;  // uniform across the row's 16 lanes
    }
    // T13 defer-max: wave-uniform skip of the O-rescale while growth < THR
    float need = fmaxf(fmaxf(mx[0] - m_i[0], mx[1] - m_i[1]),
                       fmaxf(mx[2] - m_i[2], mx[3] - m_i[3]));
    if (__any(need > DEFER_THR)) {
#pragma unroll
      for (int r = 0; r < 4; ++r) {
        float mnew = fmaxf(m_i[r], mx[r]);
        float alpha = exp2f(m_i[r] - mnew);
        lp[r] *= alpha;
        m_i[r] = mnew;
#pragma unroll
        for (int dt = 0; dt < 8; ++dt) o[dt][r] *= alpha;
      }
    }

    float p[4][4];
#pragma unroll
    for (int r = 0; r < 4; ++r) {
      float rs = 0.f;
#pragma unroll
      for (int nt = 0; nt < 4; ++nt) {
        float pv = exp2f(s[nt][r] - m_i[r]);  // bounded by 2^THR
        p[nt][r] = pv;
        rs += pv;
      }
      lp[r] += rs;
    }

    // ---- P: C-layout -> A-layout via per-wave LDS round trip ----
    bf16* pw = &Ps[wave * 16 * PST];
#pragma unroll
    for (int nt = 0; nt < 4; ++nt)
#pragma unroll
      for (int r = 0; r < 4; ++r)
        pw[(quad * 4 + r) * PST + nt * 16 + col] = (bf16)p[nt][r];
    asm volatile("s_waitcnt lgkmcnt(0)" ::: "memory");

    bf16x8 pf[2];
#pragma unroll
    for (int ks = 0; ks < 2; ++ks)
      pf[ks] = *(const bf16x8*)&pw[col * PST + ks * 32 + quad * 8];

    // ---- O += P·V (swizzled single b128 reads) ----
#pragma unroll
    for (int dt = 0; dt < 8; ++dt) {
      const char* Av = Vb + (dt * 16 + col) * 128;
#pragma unroll
      for (int ks = 0; ks < 2; ++ks) {
        bf16x8 vf = *(const bf16x8*)(Av + qx[ks]);
        o[dt] = __builtin_amdgcn_mfma_f32_16x16x32_bf16(pf[ks], vf, o[dt], 0, 0, 0);
      }
    }

    // ---- rotate: drain this iter's staging, publish buf^1 ----
    if (j < tq) {
      asm volatile("s_waitcnt vmcnt(0)" ::: "memory");
      __syncthreads();
    }
  }

  // ---- epilogue: reduce partial l across the row's 16 lanes, O / l ----
#pragma unroll
  for (int r = 0; r < 4; ++r) {
    float l = lp[r];
#pragma unroll
    for (int off = 1; off < 16; off <<= 1)
      l += __shfl_xor(l, off, 64);
    float inv = 1.f / l;
    float* orow = oh + (size_t)(q0 + wave * 16 + quad * 4 + r) * D_;
#pragma unroll
    for (int dt = 0; dt < 8; ++dt)
      orow[dt * 16 + col] = o[dt][r] * inv;
  }
}

extern "C" void kernel_launch(void* const* d_in, const int* in_sizes, int n_in,
                              void* d_out, int out_size, void* d_ws, size_t ws_size,
                              hipStream_t stream) {
  const int QN = B_ * H_ * S_ * D_;
  int qi, ki, vi;
  if (in_sizes[0] == QN)      { qi = 0; ki = 1; vi = 2; }
  else if (in_sizes[1] == QN) { qi = 1; ki = 0; vi = 2; }
  else                        { qi = 2; ki = 0; vi = 1; }
  const float* q = (const float*)d_in[qi];
  const float* k = (const float*)d_in[ki];
  const float* v = (const float*)d_in[vi];
  float* out = (float*)d_out;

  // ws: K images then V images; 2 * 16*32*8192 bf16 = 16 MiB total
  bf16* kws = (bf16*)d_ws;
  bf16* vws = kws + (size_t)(B_ * HKV_) * NTILES * TILE_ELEMS;

  prep<<<dim3(B_ * HKV_ * NTILES), dim3(256), 0, stream>>>(k, v, kws, vws);
  fa_mfma<<<dim3(2048), dim3(256), 0, stream>>>(q, kws, vws, out);
}

// Round 6
// 345.510 us; speedup vs baseline: 1.7812x; 1.1847x over previous
//
#include <hip/hip_runtime.h>
#include <hip/hip_bf16.h>
#include <cstdint>

typedef __bf16 bf16;
typedef __bf16 bf16x8 __attribute__((ext_vector_type(8)));
typedef float f32x4 __attribute__((ext_vector_type(4)));
typedef __attribute__((address_space(3))) uint32_t lds_u32;
typedef const __attribute__((address_space(1))) uint32_t glb_u32;

#define B_ 2
#define H_ 32
#define HKV_ 8
#define S_ 2048
#define D_ 128
#define QT 128                 // R6: 128 q-rows/block, 8 waves
#define KT 64
#define NQT (S_ / QT)          // 16 q-tiles
#define NTILES (S_ / KT)       // 32 k-tiles
#define TILE_ELEMS (KT * D_)   // 8192 bf16 = 16 KiB per tile image
#define PST 72                 // P LDS row stride: 144B/row, 16B-aligned
#define NEG_BIG (-1.0e30f)
#define SCL 0.12751745f        // (1/sqrt(128)) * log2(e): softmax in exp2 domain
#define DEFER_THR 8.0f         // T13: skip O-rescale while max grows < 2^8

__device__ __forceinline__ bf16x8 cvt8p(float4 a, float4 b) {
  bf16x8 r = {(bf16)a.x, (bf16)a.y, (bf16)a.z, (bf16)a.w,
              (bf16)b.x, (bf16)b.y, (bf16)b.z, (bf16)b.w};
  return r;
}
__device__ __forceinline__ bf16x8 cvt8(const float* f) {
  return cvt8p(*(const float4*)f, *(const float4*)(f + 4));
}

// ---------------- pre-pass: build swizzled bf16 LDS tile images in ws -------
// K image, per (bhkv,tile): byte(row*256 + c16*16) holds K[row][(c16^(row&7))*8 ..+7]
// V image (transposed):     byte(d*128  + c8*16)  holds V[(c8^(d&7))*8 + t][d], t=0..7
// LINEAR global->LDS copy then yields the XOR-swizzled layout (rule #21).
// R6: V transpose via LDS-staged tile -> fully coalesced global reads.
__global__ __launch_bounds__(256) void prep(const float* __restrict__ k,
                                            const float* __restrict__ v,
                                            bf16* __restrict__ kws,
                                            bf16* __restrict__ vws) {
  __shared__ float Vf[KT * 129];  // stride 129: conflict-free column reads
  const int blk = blockIdx.x;     // 512 = 16 (b*hkv) * 32 tiles
  const int bhkv = blk >> 5, tile = blk & 31;
  const float* ks = k + ((size_t)bhkv * S_ + (size_t)tile * KT) * D_;
  const float* vs = v + ((size_t)bhkv * S_ + (size_t)tile * KT) * D_;
  bf16* kd = kws + (size_t)blk * TILE_ELEMS;
  bf16* vd = vws + (size_t)blk * TILE_ELEMS;
  const int t = threadIdx.x;
#pragma unroll
  for (int i = 0; i < 8; ++i) {  // coalesced V tile -> LDS
    int c = t + 256 * i, row = c >> 5, c4 = c & 31;
    *(float4*)&Vf[row * 129 + c4 * 4] = *(const float4*)(vs + row * D_ + c4 * 4);
  }
#pragma unroll
  for (int i = 0; i < 4; ++i) {  // K image (coalesced read, linear write)
    int chunk = t + 256 * i, row = chunk >> 4, c16 = chunk & 15;
    int e = (c16 ^ (row & 7)) << 3;
    *(bf16x8*)&kd[chunk * 8] = cvt8(ks + row * D_ + e);
  }
  __syncthreads();
#pragma unroll
  for (int i = 0; i < 4; ++i) {  // V image from LDS transpose
    int chunk = t + 256 * i, d = chunk >> 3, c8 = chunk & 7;
    int k0 = (c8 ^ (d & 7)) << 3;
    bf16x8 val;
#pragma unroll
    for (int kk = 0; kk < 8; ++kk) val[kk] = (bf16)Vf[(k0 + kk) * 129 + d];
    *(bf16x8*)&vd[chunk * 8] = val;
  }
}

// ---------------- main: flash attention, QT=128 / 8 waves / 512 threads -----
// K double-buffered (read at iter top), V single-buffered (staged at iter top,
// published by the mid __syncthreads -- which also drains the DMA queue --
// read by PV at iter bottom). 2 barriers/iter serve 2x the MFMA work of R5;
// LDS 67584 B -> 2 blocks/CU -> 4 waves/SIMD (2x R5's concurrency).
__global__ __launch_bounds__(512, 4) void fa_mfma(
    const float* __restrict__ q, const bf16* __restrict__ kws,
    const bf16* __restrict__ vws, float* __restrict__ out) {
  __shared__ bf16 Kb2[2][TILE_ELEMS];  // 32 KiB
  __shared__ bf16 Vb[TILE_ELEMS];      // 16 KiB
  __shared__ bf16 Ps[8 * 16 * PST];    // 18 KiB

  const int tid = threadIdx.x, wave = tid >> 6, lane = tid & 63;
  const int col = lane & 15, quad = lane >> 4;
  const int bid = blockIdx.x;
  const int tqt = (NQT - 1) - (bid & (NQT - 1));  // diagonal-heavy first
  const int bh = bid >> 4, b = bh >> 5, h = bh & 31, hkv = h >> 2;  // GQA h/4
  const int bhkv = b * HKV_ + hkv;

  const float* qh = q + (size_t)(b * H_ + h) * S_ * D_;
  float* oh = out + (size_t)(b * H_ + h) * S_ * D_;
  const bf16* kg = kws + (size_t)(bhkv * NTILES) * TILE_ELEMS;
  const bf16* vg = vws + (size_t)(bhkv * NTILES) * TILE_ELEMS;
  const int q0 = tqt * QT;
  const int jmax = 2 * tqt + 1;  // k-tiles 0..jmax cover keys < q0+QT

  // Q A-fragments: A[m=col][k=quad*8+j], chunk ks covers d in [ks*32,ks*32+32)
  bf16x8 qf[4];
  {
    const float* qrow = qh + (size_t)(q0 + wave * 16 + col) * D_ + quad * 8;
#pragma unroll
    for (int ks = 0; ks < 4; ++ks) qf[ks] = cvt8(qrow + ks * 32);
  }

  f32x4 o[8];
#pragma unroll
  for (int i = 0; i < 8; ++i) o[i] = (f32x4){0.f, 0.f, 0.f, 0.f};
  float m_i[4], lp[4];  // lp: per-lane PARTIAL l; reduced in the epilogue
#pragma unroll
  for (int r = 0; r < 4; ++r) { m_i[r] = NEG_BIG; lp[r] = 0.f; }

  // swizzled-read offsets (same involution as prep): qx[ks] for b128 reads
  const int qoff = (quad * 16) ^ ((col & 7) << 4);
  const int qx[4] = {qoff, qoff ^ 64, qoff ^ 128, qoff ^ 192};

  const int stoff = tid * 16;  // 512 threads x 16B = 8 KiB per pass

  auto stageK = [&](int j, int buf) {
    const char* src = (const char*)(kg + (size_t)j * TILE_ELEMS) + stoff;
    char* dst = (char*)Kb2[buf] + stoff;
#pragma unroll
    for (int i = 0; i < 2; ++i)
      __builtin_amdgcn_global_load_lds((glb_u32*)(src + i * 8192),
                                       (lds_u32*)(dst + i * 8192), 16, 0, 0);
  };
  auto stageV = [&](int j) {
    const char* src = (const char*)(vg + (size_t)j * TILE_ELEMS) + stoff;
    char* dst = (char*)Vb + stoff;
#pragma unroll
    for (int i = 0; i < 2; ++i)
      __builtin_amdgcn_global_load_lds((glb_u32*)(src + i * 8192),
                                       (lds_u32*)(dst + i * 8192), 16, 0, 0);
  };

  stageK(0, 0);
  __syncthreads();  // drains DMA; K(0) visible

  for (int j = 0; j <= jmax; ++j) {
    const int cur = j & 1;
    stageV(j);                           // in flight under QK+softmax
    if (j < jmax) stageK(j + 1, cur ^ 1);  // in flight until next iter's QK

    const char* Kb = (const char*)Kb2[cur];

    // ---- S strip: 16 q-rows x 64 keys per wave (swizzled b128 reads) ----
    float s[4][4];  // S[qrow=wave*16+quad*4+r][key=nt*16+col]
    __builtin_amdgcn_s_setprio(1);
#pragma unroll
    for (int nt = 0; nt < 4; ++nt) {
      const char* An = Kb + (nt * 16 + col) * 256;
      f32x4 acc = (f32x4){0.f, 0.f, 0.f, 0.f};
#pragma unroll
      for (int ks = 0; ks < 4; ++ks) {
        bf16x8 kf = *(const bf16x8*)(An + qx[ks]);
        acc = __builtin_amdgcn_mfma_f32_16x16x32_bf16(qf[ks], kf, acc, 0, 0, 0);
      }
#pragma unroll
      for (int r = 0; r < 4; ++r) s[nt][r] = acc[r] * SCL;
    }
    __builtin_amdgcn_s_setprio(0);

    // causal mask: only the last two k-tiles intersect the diagonal
    if (j >= 2 * tqt) {
      const int rel = j * KT - q0 - wave * 16;  // key offset vs wave's row base
#pragma unroll
      for (int nt = 0; nt < 4; ++nt) {
        int kc = rel + nt * 16 + col;
#pragma unroll
        for (int r = 0; r < 4; ++r)
          if (kc > quad * 4 + r) s[nt][r] = NEG_BIG;
      }
    }

    // ---- online softmax: max-reduce only; l kept as per-lane partial ----
    float mx[4];
#pragma unroll
    for (int r = 0; r < 4; ++r) {
      float m0 = fmaxf(fmaxf(s[0][r], s[1][r]), fmaxf(s[2][r], s[3][r]));
#pragma unroll
      for (int off = 1; off < 16; off <<= 1)
        m0 = fmaxf(m0, __shfl_xor(m0, off, 64));
      mx[r] = m0;  // uniform across the row's 16 lanes
    }
    // T13 defer-max: wave-uniform skip of the O-rescale while growth < THR
    float need = fmaxf(fmaxf(mx[0] - m_i[0], mx[1] - m_i[1]),
                       fmaxf(mx[2] - m_i[2], mx[3] - m_i[3]));
    if (__any(need > DEFER_THR)) {
#pragma unroll
      for (int r = 0; r < 4; ++r) {
        float mnew = fmaxf(m_i[r], mx[r]);
        float alpha = exp2f(m_i[r] - mnew);
        lp[r] *= alpha;
        m_i[r] = mnew;
#pragma unroll
        for (int dt = 0; dt < 8; ++dt) o[dt][r] *= alpha;
      }
    }

    float p[4][4];
#pragma unroll
    for (int r = 0; r < 4; ++r) {
      float rs = 0.f;
#pragma unroll
      for (int nt = 0; nt < 4; ++nt) {
        float pv = exp2f(s[nt][r] - m_i[r]);  // bounded by 2^THR
        p[nt][r] = pv;
        rs += pv;
      }
      lp[r] += rs;
    }

    // ---- P: C-layout -> A-layout via per-wave LDS round trip ----
    bf16* pw = &Ps[wave * 16 * PST];
#pragma unroll
    for (int nt = 0; nt < 4; ++nt)
#pragma unroll
      for (int r = 0; r < 4; ++r)
        pw[(quad * 4 + r) * PST + nt * 16 + col] = (bf16)p[nt][r];

    // mid barrier: drains DMA queue (V(j) staged, K(j+1) staged) + P visible
    __syncthreads();

    bf16x8 pf[2];
#pragma unroll
    for (int ks = 0; ks < 2; ++ks)
      pf[ks] = *(const bf16x8*)&pw[col * PST + ks * 32 + quad * 8];

    // ---- O += P·V (swizzled single b128 reads) ----
    __builtin_amdgcn_s_setprio(1);
#pragma unroll
    for (int dt = 0; dt < 8; ++dt) {
      const char* Av = (const char*)Vb + (dt * 16 + col) * 128;
#pragma unroll
      for (int ks = 0; ks < 2; ++ks) {
        bf16x8 vf = *(const bf16x8*)(Av + qx[ks]);
        o[dt] = __builtin_amdgcn_mfma_f32_16x16x32_bf16(pf[ks], vf, o[dt], 0, 0, 0);
      }
    }
    __builtin_amdgcn_s_setprio(0);

    // end barrier: all waves done reading Vb & Kb2[cur] before overwrite
    if (j < jmax) __syncthreads();
  }

  // ---- epilogue: reduce partial l across the row's 16 lanes, O / l ----
#pragma unroll
  for (int r = 0; r < 4; ++r) {
    float l = lp[r];
#pragma unroll
    for (int off = 1; off < 16; off <<= 1)
      l += __shfl_xor(l, off, 64);
    float inv = 1.f / l;
    float* orow = oh + (size_t)(q0 + wave * 16 + quad * 4 + r) * D_;
#pragma unroll
    for (int dt = 0; dt < 8; ++dt)
      orow[dt * 16 + col] = o[dt][r] * inv;
  }
}

extern "C" void kernel_launch(void* const* d_in, const int* in_sizes, int n_in,
                              void* d_out, int out_size, void* d_ws, size_t ws_size,
                              hipStream_t stream) {
  const int QN = B_ * H_ * S_ * D_;
  int qi, ki, vi;
  if (in_sizes[0] == QN)      { qi = 0; ki = 1; vi = 2; }
  else if (in_sizes[1] == QN) { qi = 1; ki = 0; vi = 2; }
  else                        { qi = 2; ki = 0; vi = 1; }
  const float* q = (const float*)d_in[qi];
  const float* k = (const float*)d_in[ki];
  const float* v = (const float*)d_in[vi];
  float* out = (float*)d_out;

  // ws: K images then V images; 2 * 16*32*8192 bf16 = 16 MiB total
  bf16* kws = (bf16*)d_ws;
  bf16* vws = kws + (size_t)(B_ * HKV_) * NTILES * TILE_ELEMS;

  prep<<<dim3(B_ * HKV_ * NTILES), dim3(256), 0, stream>>>(k, v, kws, vws);
  fa_mfma<<<dim3(B_ * H_ * NQT), dim3(512), 0, stream>>>(q, kws, vws, out);
}

// Round 7
// 343.955 us; speedup vs baseline: 1.7892x; 1.0045x over previous
//
#include <hip/hip_runtime.h>
#include <hip/hip_bf16.h>
#include <cstdint>

typedef __bf16 bf16;
typedef __bf16 bf16x8 __attribute__((ext_vector_type(8)));
typedef float f32x4 __attribute__((ext_vector_type(4)));
typedef __attribute__((address_space(3))) uint32_t lds_u32;
typedef const __attribute__((address_space(1))) uint32_t glb_u32;

#define B_ 2
#define H_ 32
#define HKV_ 8
#define S_ 2048
#define D_ 128
#define QT 128                 // 128 q-rows/block, 8 waves
#define KT 64
#define NQT (S_ / QT)          // 16 q-tiles
#define NTILES (S_ / KT)       // 32 k-tiles
#define TILE_ELEMS (KT * D_)   // 8192 bf16 = 16 KiB per tile image
#define PST 72                 // P LDS row stride: 144B/row, 16B-aligned
#define NEG_BIG (-1.0e30f)
#define SCL 0.12751745f        // (1/sqrt(128)) * log2(e): softmax in exp2 domain
#define DEFER_THR 8.0f         // T13: skip O-rescale while max grows < 2^8

__device__ __forceinline__ bf16x8 cvt8p(float4 a, float4 b) {
  bf16x8 r = {(bf16)a.x, (bf16)a.y, (bf16)a.z, (bf16)a.w,
              (bf16)b.x, (bf16)b.y, (bf16)b.z, (bf16)b.w};
  return r;
}
__device__ __forceinline__ bf16x8 cvt8(const float* f) {
  return cvt8p(*(const float4*)f, *(const float4*)(f + 4));
}

// ---------------- pre-pass: build swizzled bf16 LDS tile images in ws -------
// K image, per (bhkv,tile): byte(row*256 + c16*16) holds K[row][(c16^(row&7))*8 ..+7]
// V image (transposed):     byte(d*128  + c8*16)  holds V[(c8^(d&7))*8 + t][d], t=0..7
// LINEAR global->LDS copy then yields the XOR-swizzled layout (rule #21).
// R7: 512 threads/block (R6's 256 left the launch 4x under-filled; prep was
// ~85us of the 345 total, pure parallelism-limited).
__global__ __launch_bounds__(512) void prep(const float* __restrict__ k,
                                            const float* __restrict__ v,
                                            bf16* __restrict__ kws,
                                            bf16* __restrict__ vws) {
  __shared__ float Vf[KT * 129];  // stride 129: conflict-free column reads
  const int blk = blockIdx.x;     // 512 = 16 (b*hkv) * 32 tiles
  const int bhkv = blk >> 5, tile = blk & 31;
  const float* ks = k + ((size_t)bhkv * S_ + (size_t)tile * KT) * D_;
  const float* vs = v + ((size_t)bhkv * S_ + (size_t)tile * KT) * D_;
  bf16* kd = kws + (size_t)blk * TILE_ELEMS;
  bf16* vd = vws + (size_t)blk * TILE_ELEMS;
  const int t = threadIdx.x;
#pragma unroll
  for (int i = 0; i < 4; ++i) {  // coalesced V tile -> LDS (2048 float4 chunks)
    int c = t + 512 * i, row = c >> 5, c4 = c & 31;
    *(float4*)&Vf[row * 129 + c4 * 4] = *(const float4*)(vs + row * D_ + c4 * 4);
  }
#pragma unroll
  for (int i = 0; i < 2; ++i) {  // K image (coalesced read, linear write)
    int chunk = t + 512 * i, row = chunk >> 4, c16 = chunk & 15;
    int e = (c16 ^ (row & 7)) << 3;
    *(bf16x8*)&kd[chunk * 8] = cvt8(ks + row * D_ + e);
  }
  __syncthreads();
#pragma unroll
  for (int i = 0; i < 2; ++i) {  // V image from LDS transpose
    int chunk = t + 512 * i, d = chunk >> 3, c8 = chunk & 7;
    int k0 = (c8 ^ (d & 7)) << 3;
    bf16x8 val;
#pragma unroll
    for (int kk = 0; kk < 8; ++kk) val[kk] = (bf16)Vf[(k0 + kk) * 129 + d];
    *(bf16x8*)&vd[chunk * 8] = val;
  }
}

// ---------------- main: flash attention, QT=128 / 8 waves / 512 threads -----
// R7: T4 counted vmcnt + raw s_barrier. __syncthreads forced vmcnt(0) at the
// mid barrier, draining K(j+1)'s DMA half an iteration early and stalling all
// waves on the full queue. Now: mid = vmcnt(2) (V(j) done, K(j+1) in flight),
// end = vmcnt(0) (K covered by the whole PV phase).
__global__ __launch_bounds__(512, 4) void fa_mfma(
    const float* __restrict__ q, const bf16* __restrict__ kws,
    const bf16* __restrict__ vws, float* __restrict__ out) {
  __shared__ bf16 Kb2[2][TILE_ELEMS];  // 32 KiB
  __shared__ bf16 Vb[TILE_ELEMS];      // 16 KiB
  __shared__ bf16 Ps[8 * 16 * PST];    // 18 KiB

  const int tid = threadIdx.x, wave = tid >> 6, lane = tid & 63;
  const int col = lane & 15, quad = lane >> 4;
  const int bid = blockIdx.x;
  const int tqt = (NQT - 1) - (bid & (NQT - 1));  // diagonal-heavy first
  const int bh = bid >> 4, b = bh >> 5, h = bh & 31, hkv = h >> 2;  // GQA h/4
  const int bhkv = b * HKV_ + hkv;

  const float* qh = q + (size_t)(b * H_ + h) * S_ * D_;
  float* oh = out + (size_t)(b * H_ + h) * S_ * D_;
  const bf16* kg = kws + (size_t)(bhkv * NTILES) * TILE_ELEMS;
  const bf16* vg = vws + (size_t)(bhkv * NTILES) * TILE_ELEMS;
  const int q0 = tqt * QT;
  const int jmax = 2 * tqt + 1;  // k-tiles 0..jmax cover keys < q0+QT

  // Q A-fragments: A[m=col][k=quad*8+j], chunk ks covers d in [ks*32,ks*32+32)
  bf16x8 qf[4];
  {
    const float* qrow = qh + (size_t)(q0 + wave * 16 + col) * D_ + quad * 8;
#pragma unroll
    for (int ks = 0; ks < 4; ++ks) qf[ks] = cvt8(qrow + ks * 32);
  }

  f32x4 o[8];
#pragma unroll
  for (int i = 0; i < 8; ++i) o[i] = (f32x4){0.f, 0.f, 0.f, 0.f};
  float m_i[4], lp[4];  // lp: per-lane PARTIAL l; reduced in the epilogue
#pragma unroll
  for (int r = 0; r < 4; ++r) { m_i[r] = NEG_BIG; lp[r] = 0.f; }

  // swizzled-read offsets (same involution as prep): qx[ks] for b128 reads
  const int qoff = (quad * 16) ^ ((col & 7) << 4);
  const int qx[4] = {qoff, qoff ^ 64, qoff ^ 128, qoff ^ 192};

  const int stoff = tid * 16;  // 512 threads x 16B = 8 KiB per pass

  auto stageK = [&](int j, int buf) {
    const char* src = (const char*)(kg + (size_t)j * TILE_ELEMS) + stoff;
    char* dst = (char*)Kb2[buf] + stoff;
#pragma unroll
    for (int i = 0; i < 2; ++i)
      __builtin_amdgcn_global_load_lds((glb_u32*)(src + i * 8192),
                                       (lds_u32*)(dst + i * 8192), 16, 0, 0);
  };
  auto stageV = [&](int j) {
    const char* src = (const char*)(vg + (size_t)j * TILE_ELEMS) + stoff;
    char* dst = (char*)Vb + stoff;
#pragma unroll
    for (int i = 0; i < 2; ++i)
      __builtin_amdgcn_global_load_lds((glb_u32*)(src + i * 8192),
                                       (lds_u32*)(dst + i * 8192), 16, 0, 0);
  };

  stageK(0, 0);
  asm volatile("s_waitcnt vmcnt(0)" ::: "memory");
  __builtin_amdgcn_s_barrier();
  __builtin_amdgcn_sched_barrier(0);

  for (int j = 0; j <= jmax; ++j) {
    const int cur = j & 1;
    stageV(j);                             // needed at mid barrier
    if (j < jmax) stageK(j + 1, cur ^ 1);  // needed at end barrier

    const char* Kb = (const char*)Kb2[cur];

    // ---- S strip: 16 q-rows x 64 keys per wave (swizzled b128 reads) ----
    float s[4][4];  // S[qrow=wave*16+quad*4+r][key=nt*16+col]
    __builtin_amdgcn_s_setprio(1);
#pragma unroll
    for (int nt = 0; nt < 4; ++nt) {
      const char* An = Kb + (nt * 16 + col) * 256;
      f32x4 acc = (f32x4){0.f, 0.f, 0.f, 0.f};
#pragma unroll
      for (int ks = 0; ks < 4; ++ks) {
        bf16x8 kf = *(const bf16x8*)(An + qx[ks]);
        acc = __builtin_amdgcn_mfma_f32_16x16x32_bf16(qf[ks], kf, acc, 0, 0, 0);
      }
#pragma unroll
      for (int r = 0; r < 4; ++r) s[nt][r] = acc[r] * SCL;
    }
    __builtin_amdgcn_s_setprio(0);

    // causal mask: only the last two k-tiles intersect the diagonal
    if (j >= 2 * tqt) {
      const int rel = j * KT - q0 - wave * 16;  // key offset vs wave's row base
#pragma unroll
      for (int nt = 0; nt < 4; ++nt) {
        int kc = rel + nt * 16 + col;
#pragma unroll
        for (int r = 0; r < 4; ++r)
          if (kc > quad * 4 + r) s[nt][r] = NEG_BIG;
      }
    }

    // ---- online softmax: max-reduce only; l kept as per-lane partial ----
    float mx[4];
#pragma unroll
    for (int r = 0; r < 4; ++r) {
      float m0 = fmaxf(fmaxf(s[0][r], s[1][r]), fmaxf(s[2][r], s[3][r]));
#pragma unroll
      for (int off = 1; off < 16; off <<= 1)
        m0 = fmaxf(m0, __shfl_xor(m0, off, 64));
      mx[r] = m0;  // uniform across the row's 16 lanes
    }
    // T13 defer-max: wave-uniform skip of the O-rescale while growth < THR
    float need = fmaxf(fmaxf(mx[0] - m_i[0], mx[1] - m_i[1]),
                       fmaxf(mx[2] - m_i[2], mx[3] - m_i[3]));
    if (__any(need > DEFER_THR)) {
#pragma unroll
      for (int r = 0; r < 4; ++r) {
        float mnew = fmaxf(m_i[r], mx[r]);
        float alpha = exp2f(m_i[r] - mnew);
        lp[r] *= alpha;
        m_i[r] = mnew;
#pragma unroll
        for (int dt = 0; dt < 8; ++dt) o[dt][r] *= alpha;
      }
    }

    float p[4][4];
#pragma unroll
    for (int r = 0; r < 4; ++r) {
      float rs = 0.f;
#pragma unroll
      for (int nt = 0; nt < 4; ++nt) {
        float pv = exp2f(s[nt][r] - m_i[r]);  // bounded by 2^THR
        p[nt][r] = pv;
        rs += pv;
      }
      lp[r] += rs;
    }

    // ---- P: C-layout -> A-layout via per-wave LDS round trip ----
    bf16* pw = &Ps[wave * 16 * PST];
#pragma unroll
    for (int nt = 0; nt < 4; ++nt)
#pragma unroll
      for (int r = 0; r < 4; ++r)
        pw[(quad * 4 + r) * PST + nt * 16 + col] = (bf16)p[nt][r];

    // mid barrier (counted): V(j) + own P visible; K(j+1) stays in flight
    if (j < jmax)
      asm volatile("s_waitcnt vmcnt(2) lgkmcnt(0)" ::: "memory");
    else
      asm volatile("s_waitcnt vmcnt(0) lgkmcnt(0)" ::: "memory");
    __builtin_amdgcn_s_barrier();
    __builtin_amdgcn_sched_barrier(0);

    bf16x8 pf[2];
#pragma unroll
    for (int ks = 0; ks < 2; ++ks)
      pf[ks] = *(const bf16x8*)&pw[col * PST + ks * 32 + quad * 8];

    // ---- O += P·V (swizzled single b128 reads) ----
    __builtin_amdgcn_s_setprio(1);
#pragma unroll
    for (int dt = 0; dt < 8; ++dt) {
      const char* Av = (const char*)Vb + (dt * 16 + col) * 128;
#pragma unroll
      for (int ks = 0; ks < 2; ++ks) {
        bf16x8 vf = *(const bf16x8*)(Av + qx[ks]);
        o[dt] = __builtin_amdgcn_mfma_f32_16x16x32_bf16(pf[ks], vf, o[dt], 0, 0, 0);
      }
    }
    __builtin_amdgcn_s_setprio(0);

    // end barrier: K(j+1) drained (covered by PV); LDS safe to overwrite
    if (j < jmax) {
      asm volatile("s_waitcnt vmcnt(0)" ::: "memory");
      __builtin_amdgcn_s_barrier();
      __builtin_amdgcn_sched_barrier(0);
    }
  }

  // ---- epilogue: reduce partial l across the row's 16 lanes, O / l ----
#pragma unroll
  for (int r = 0; r < 4; ++r) {
    float l = lp[r];
#pragma unroll
    for (int off = 1; off < 16; off <<= 1)
      l += __shfl_xor(l, off, 64);
    float inv = 1.f / l;
    float* orow = oh + (size_t)(q0 + wave * 16 + quad * 4 + r) * D_;
#pragma unroll
    for (int dt = 0; dt < 8; ++dt)
      orow[dt * 16 + col] = o[dt][r] * inv;
  }
}

extern "C" void kernel_launch(void* const* d_in, const int* in_sizes, int n_in,
                              void* d_out, int out_size, void* d_ws, size_t ws_size,
                              hipStream_t stream) {
  const int QN = B_ * H_ * S_ * D_;
  int qi, ki, vi;
  if (in_sizes[0] == QN)      { qi = 0; ki = 1; vi = 2; }
  else if (in_sizes[1] == QN) { qi = 1; ki = 0; vi = 2; }
  else                        { qi = 2; ki = 0; vi = 1; }
  const float* q = (const float*)d_in[qi];
  const float* k = (const float*)d_in[ki];
  const float* v = (const float*)d_in[vi];
  float* out = (float*)d_out;

  // ws: K images then V images; 2 * 16*32*8192 bf16 = 16 MiB total
  bf16* kws = (bf16*)d_ws;
  bf16* vws = kws + (size_t)(B_ * HKV_) * NTILES * TILE_ELEMS;

  prep<<<dim3(B_ * HKV_ * NTILES), dim3(512), 0, stream>>>(k, v, kws, vws);
  fa_mfma<<<dim3(B_ * H_ * NQT), dim3(512), 0, stream>>>(q, kws, vws, out);
}